// Round 15
// baseline (136.527 us; speedup 1.0000x reference)
//
#include <hip/hip_runtime.h>
#include <stdint.h>

#define DIM   128
#define NK    512
#define SPB   32768
#define NBLK  1024

#define E_OFF 16777216
#define D_OFF 83886080
#define L_OFF 150994944

typedef __attribute__((ext_vector_type(16))) float f32x16;
typedef __attribute__((ext_vector_type(4)))  float f32x4;
typedef __attribute__((ext_vector_type(8)))  short bf16x8;

__device__ __forceinline__ unsigned int rne_bf16(float f) {
    union { float f; unsigned int u; } v; v.f = f;
    return (v.u + 0x7FFFu + ((v.u >> 16) & 1u)) >> 16;
}
__device__ __forceinline__ float bf16f(unsigned int h) {
    union { float f; unsigned int u; } v; v.u = h << 16;
    return v.f;
}
__device__ __forceinline__ unsigned int f2u(float f) {
    union { float f; unsigned int u; } v; v.f = f; return v.u;
}
__device__ __forceinline__ float u2f(unsigned int u) {
    union { float f; unsigned int u; } v; v.u = u; return v.f;
}

// Pre-kernel: codebook bf16-rounded + sq-norms OF THE ROUNDED rows (dist =
// exact distance between rounded vectors + code-independent offset).
// Fragment-major: index ((c*8+t)*64 + lane), 8 bf16/lane.
// Also zero-inits the loss accumulator (re-zeroed every call -> replay-safe).
__global__ __launch_bounds__(256) void prep_kernel(
        const float* __restrict__ cb, float* __restrict__ ww,
        short* __restrict__ cbh, float* __restrict__ out) {
    const int tid = blockIdx.x * 256 + threadIdx.x;   // 0..8191
    if (tid == 0) out[L_OFF] = 0.0f;
    if (tid < NK) {
        const float* row = cb + tid * DIM;
        float s = 0.f;
        #pragma unroll 8
        for (int d = 0; d < DIM; ++d) {
            float r = bf16f(rne_bf16(row[d]));
            s = fmaf(r, r, s);
        }
        ww[tid] = s;
    }
    const int l = tid & 63;
    const int t = (tid >> 6) & 7;
    const int c = tid >> 9;
    const float* src = cb + (c * 32 + (l & 31)) * DIM + t * 16 + ((l >> 5) << 3);
    bf16x8 vh;
    #pragma unroll
    for (int j = 0; j < 8; ++j) vh[j] = (short)rne_bf16(src[j]);
    ((bf16x8*)cbh)[tid] = vh;
}

__global__ __launch_bounds__(256, 4) void vq_main(
        const float* __restrict__ x, const float* __restrict__ cb,
        const float* __restrict__ ww,
        const short* __restrict__ cbh,
        float* __restrict__ out) {
    __shared__ unsigned short xtile[16384];   // 32KB rounded-bf16 x tile [d][s]
    __shared__ int   idx_s[128];
    __shared__ float red_s[128];

    const int tid  = threadIdx.x;
    const int bid  = blockIdx.x;
    const int lane = tid & 63;
    const int w    = tid >> 6;
    const int bb   = bid >> 8;            // batch index (256 blocks per batch elem)
    const int s0   = (bid & 255) << 7;    // spatial base
    const int hi4  = (lane >> 5) << 2;
    const int rloc = (w << 5) + (lane & 31);   // this lane's x row (0..127)
    const int kb   = (lane >> 5) << 3;         // k-offset 0 or 8

    const float* xb = x + (size_t)bb * (DIM * SPB) + s0;

    // ---- phase 1a: coalesced f32x4 x loads (2x512B contiguous per instr,
    //      page-sequential within d-planes), round, stage bf16 [d][s] tile
    #pragma unroll
    for (int it = 0; it < 16; ++it) {
        int i4 = tid + it * 256;          // 0..4095 f32x4 slots
        int d  = i4 >> 5;
        int o  = (i4 & 31) << 2;
        f32x4 v = __builtin_nontemporal_load((const f32x4*)(xb + (size_t)d * SPB + o));
        unsigned int p0 = rne_bf16(v[0]) | (rne_bf16(v[1]) << 16);
        unsigned int p1 = rne_bf16(v[2]) | (rne_bf16(v[3]) << 16);
        unsigned int* dst = (unsigned int*)&xtile[d * 128 + o];
        dst[0] = p0;
        dst[1] = p1;
    }
    __syncthreads();

    // ---- phase 1b: fragments from LDS (u16 reads, <=2-way = free) + rounded norm
    bf16x8 ah[8];
    float xxl = 0.f;
    #pragma unroll
    for (int t = 0; t < 8; ++t) {
        bf16x8 vh;
        #pragma unroll
        for (int j = 0; j < 8; ++j) {
            unsigned short u = xtile[(t * 16 + kb + j) * 128 + rloc];
            float f = bf16f(u);
            xxl = fmaf(f, f, xxl);
            vh[j] = (short)u;
        }
        ah[t] = vh;
    }
    // full rounded row norm: lane & lane^32 hold complementary k-halves
    xxl += __shfl_xor(xxl, 32, 64);
    float xxr[16];
    #pragma unroll
    for (int r = 0; r < 16; ++r)
        xxr[r] = __shfl(xxl, (r & 3) + ((r >> 2) << 3) + hi4, 64);

    unsigned int best[16];
    #pragma unroll
    for (int r = 0; r < 16; ++r) best[r] = 0xFFFFFFFFu;

    const int col = lane & 31;
    const int rowbase = bid * 128 + (w << 5);

    // ---- main loop: 16 col-tiles of 32 codes; single-term bf16 MFMA; no barriers
    for (int c = 0; c < 16; ++c) {
        f32x16 acc = {};
        const bf16x8* ph = (const bf16x8*)cbh + c * 512 + lane;
        #pragma unroll
        for (int t = 0; t < 8; ++t) {
            bf16x8 bh = ph[t * 64];
            acc = __builtin_amdgcn_mfma_f32_32x32x16_bf16(ah[t], bh, acc, 0, 0, 0);
        }
        const int kcol = (c << 5) + col;
        const float wwc = ww[kcol];
        #pragma unroll
        for (int r = 0; r < 16; ++r) {
            float dist = fmaf(-2.f, acc[r], xxr[r] + wwc);
            int rl = (r & 3) + ((r >> 2) << 3) + hi4;
            __builtin_nontemporal_store(dist,
                &out[(size_t)D_OFF + (size_t)(rowbase + rl) * NK + kcol]);
            unsigned int pack = (f2u(dist) & ~511u) | (unsigned int)kcol;
            best[r] = pack < best[r] ? pack : best[r];
        }
    }

    // ---- argmin: u32 shuffle-min over the 32-lane column group
    #pragma unroll
    for (int r = 0; r < 16; ++r) {
        unsigned int b = best[r];
        #pragma unroll
        for (int m = 16; m >= 1; m >>= 1) {
            unsigned int ob = __shfl_xor(b, m, 64);
            b = ob < b ? ob : b;
        }
        best[r] = b;
    }
    if ((lane & 31) == 0) {
        #pragma unroll
        for (int r = 0; r < 16; ++r) {
            int row = (w << 5) + (r & 3) + ((r >> 2) << 3) + hi4;
            idx_s[row] = (int)(best[r] & 511u);
            red_s[row] = u2f(best[r] & ~511u);
        }
    }
    __syncthreads();

    // ---- loss partial (wave 0): one scaled atomicAdd per block
    if (tid < 64) {
        float s = red_s[tid] + red_s[tid + 64];
        #pragma unroll
        for (int m = 32; m >= 1; m >>= 1) s += __shfl_xor(s, m, 64);
        if (tid == 0) atomicAdd(&out[L_OFF], s * (2.0f / 16777216.0f));
    }

    // ---- quantized: gather cb row to regs, scalar column stores (2x128B/inst)
    {
        int r = tid >> 1, h = tid & 1;
        const float* src = cb + (size_t)idx_s[r] * DIM + h * 64;
        float* ob = out + (size_t)bb * (DIM * SPB) + s0 + r;
        #pragma unroll
        for (int q = 0; q < 16; ++q) {
            f32x4 v = *(const f32x4*)(src + (q << 2));
            #pragma unroll
            for (int e = 0; e < 4; ++e) {
                int d = h * 64 + (q << 2) + e;
                __builtin_nontemporal_store(v[e], &ob[(size_t)d * SPB]);
            }
        }
    }

    // ---- encoding one-hot: fused zero+one-hot, lane-contiguous f32x4 nt stores
    {
        float* ebase = out + (size_t)E_OFF + (size_t)bid * (128 * NK);
        #pragma unroll
        for (int j = 0; j < 64; ++j) {
            int v   = j * 256 + tid;       // f32x4 index within block's 128x512 region
            int r   = v >> 7;
            int cb4 = (v & 127) << 2;
            int idxr = idx_s[r];
            f32x4 val;
            val[0] = (idxr == cb4    ) ? 1.0f : 0.0f;
            val[1] = (idxr == cb4 + 1) ? 1.0f : 0.0f;
            val[2] = (idxr == cb4 + 2) ? 1.0f : 0.0f;
            val[3] = (idxr == cb4 + 3) ? 1.0f : 0.0f;
            __builtin_nontemporal_store(val, (f32x4*)ebase + v);
        }
    }
}

extern "C" void kernel_launch(void* const* d_in, const int* in_sizes, int n_in,
                              void* d_out, int out_size, void* d_ws, size_t ws_size,
                              hipStream_t stream) {
    const float* x  = (const float*)d_in[0];
    const float* cb = (const float*)d_in[1];
    float* out = (float*)d_out;
    char*  ws  = (char*)d_ws;
    float* ww  = (float*)ws;                          // 2048 B
    short* cbh = (short*)(ws + 2048);                 // 131072 B

    prep_kernel<<<32, 256, 0, stream>>>(cb, ww, cbh, out);
    vq_main<<<NBLK, 256, 0, stream>>>(x, cb, ww, cbh, out);
}

// Round 16
// 130.314 us; speedup vs baseline: 1.0477x; 1.0477x over previous
//
#include <hip/hip_runtime.h>
#include <stdint.h>

#define DIM   128
#define NK    512
#define SPB   32768
#define NBLK  1024

#define E_OFF 16777216
#define D_OFF 83886080
#define L_OFF 150994944

typedef __attribute__((ext_vector_type(16))) float f32x16;
typedef __attribute__((ext_vector_type(4)))  float f32x4;
typedef __attribute__((ext_vector_type(8)))  short bf16x8;

__device__ __forceinline__ unsigned int rne_bf16(float f) {
    union { float f; unsigned int u; } v; v.f = f;
    return (v.u + 0x7FFFu + ((v.u >> 16) & 1u)) >> 16;
}
__device__ __forceinline__ float bf16f(unsigned int h) {
    union { float f; unsigned int u; } v; v.u = h << 16;
    return v.f;
}
__device__ __forceinline__ unsigned int f2u(float f) {
    union { float f; unsigned int u; } v; v.f = f; return v.u;
}
__device__ __forceinline__ float u2f(unsigned int u) {
    union { float f; unsigned int u; } v; v.u = u; return v.f;
}

// Pre-kernel: codebook bf16-rounded + sq-norms OF THE ROUNDED rows (dist =
// exact distance between rounded vectors + code-independent offset).
// Fragment-major: index ((c*8+t)*64 + lane), 8 bf16/lane.
// Also zero-inits the loss accumulator (re-zeroed every call -> replay-safe).
__global__ __launch_bounds__(256) void prep_kernel(
        const float* __restrict__ cb, float* __restrict__ ww,
        short* __restrict__ cbh, float* __restrict__ out) {
    const int tid = blockIdx.x * 256 + threadIdx.x;   // 0..8191
    if (tid == 0) out[L_OFF] = 0.0f;
    if (tid < NK) {
        const float* row = cb + tid * DIM;
        float s = 0.f;
        #pragma unroll 8
        for (int d = 0; d < DIM; ++d) {
            float r = bf16f(rne_bf16(row[d]));
            s = fmaf(r, r, s);
        }
        ww[tid] = s;
    }
    const int l = tid & 63;
    const int t = (tid >> 6) & 7;
    const int c = tid >> 9;
    const float* src = cb + (c * 32 + (l & 31)) * DIM + t * 16 + ((l >> 5) << 3);
    bf16x8 vh;
    #pragma unroll
    for (int j = 0; j < 8; ++j) vh[j] = (short)rne_bf16(src[j]);
    ((bf16x8*)cbh)[tid] = vh;
}

__global__ __launch_bounds__(256, 4) void vq_main(
        const float* __restrict__ x, const float* __restrict__ cb,
        const float* __restrict__ ww,
        const short* __restrict__ cbh,
        float* __restrict__ out) {
    __shared__ float xx_s[128];
    __shared__ int   idx_s[128];
    __shared__ float red_s[128];

    const int tid  = threadIdx.x;
    const int bid  = blockIdx.x;
    const int lane = tid & 63;
    const int w    = tid >> 6;
    const int bb   = bid >> 8;            // batch index (256 blocks per batch elem)
    const int s0   = (bid & 255) << 7;    // spatial base
    const int hi4  = (lane >> 5) << 2;
    const int rloc = (w << 5) + (lane & 31);   // this lane's x row (0..127)
    const int kb   = (lane >> 5) << 3;         // k-offset 0 or 8

    const float* xrow = x + (size_t)bb * (DIM * SPB) + s0 + rloc;

    // ---- phase 1: direct global fragment loads (nt) + bf16 round + true norm
    bf16x8 ah[8];
    float xxl = 0.f;
    #pragma unroll
    for (int t = 0; t < 8; ++t) {
        bf16x8 vh;
        #pragma unroll
        for (int j = 0; j < 8; ++j) {
            float f = __builtin_nontemporal_load(xrow + (size_t)(t * 16 + kb + j) * SPB);
            xxl = fmaf(f, f, xxl);
            vh[j] = (short)rne_bf16(f);
        }
        ah[t] = vh;
    }
    // full row norm: lane and lane^32 share a row, complementary k-halves
    xxl += __shfl_xor(xxl, 32, 64);
    if (lane < 32) xx_s[rloc] = xxl;
    __syncthreads();

    float xxr[16];
    #pragma unroll
    for (int r = 0; r < 16; ++r)
        xxr[r] = xx_s[(w << 5) + (r & 3) + ((r >> 2) << 3) + hi4];

    unsigned int best[16];
    #pragma unroll
    for (int r = 0; r < 16; ++r) best[r] = 0xFFFFFFFFu;

    const int col = lane & 31;
    const int rowbase = bid * 128 + (w << 5);

    // ---- main loop: 16 col-tiles of 32 codes; single-term bf16 MFMA; no barriers
    for (int c = 0; c < 16; ++c) {
        f32x16 acc = {};
        const bf16x8* ph = (const bf16x8*)cbh + c * 512 + lane;
        #pragma unroll
        for (int t = 0; t < 8; ++t) {
            bf16x8 bh = ph[t * 64];
            acc = __builtin_amdgcn_mfma_f32_32x32x16_bf16(ah[t], bh, acc, 0, 0, 0);
        }
        const int kcol = (c << 5) + col;
        const float wwc = ww[kcol];
        #pragma unroll
        for (int r = 0; r < 16; ++r) {
            float dist = fmaf(-2.f, acc[r], xxr[r] + wwc);
            int rl = (r & 3) + ((r >> 2) << 3) + hi4;
            __builtin_nontemporal_store(dist,
                &out[(size_t)D_OFF + (size_t)(rowbase + rl) * NK + kcol]);
            unsigned int pack = (f2u(dist) & ~511u) | (unsigned int)kcol;
            best[r] = pack < best[r] ? pack : best[r];
        }
    }

    // ---- argmin: u32 shuffle-min over the 32-lane column group
    #pragma unroll
    for (int r = 0; r < 16; ++r) {
        unsigned int b = best[r];
        #pragma unroll
        for (int m = 16; m >= 1; m >>= 1) {
            unsigned int ob = __shfl_xor(b, m, 64);
            b = ob < b ? ob : b;
        }
        best[r] = b;
    }
    if ((lane & 31) == 0) {
        #pragma unroll
        for (int r = 0; r < 16; ++r) {
            int row = (w << 5) + (r & 3) + ((r >> 2) << 3) + hi4;
            idx_s[row] = (int)(best[r] & 511u);
            red_s[row] = u2f(best[r] & ~511u);
        }
    }
    __syncthreads();

    // ---- loss partial (wave 0): one scaled atomicAdd per block (no loss kernel)
    if (tid < 64) {
        float s = red_s[tid] + red_s[tid + 64];
        #pragma unroll
        for (int m = 32; m >= 1; m >>= 1) s += __shfl_xor(s, m, 64);
        if (tid == 0) atomicAdd(&out[L_OFF], s * (2.0f / 16777216.0f));
    }

    // ---- quantized: gather cb row to regs, scalar column stores (2x128B/inst)
    {
        int r = tid >> 1, h = tid & 1;
        const float* src = cb + (size_t)idx_s[r] * DIM + h * 64;
        float* ob = out + (size_t)bb * (DIM * SPB) + s0 + r;
        #pragma unroll
        for (int q = 0; q < 16; ++q) {
            f32x4 v = *(const f32x4*)(src + (q << 2));
            #pragma unroll
            for (int e = 0; e < 4; ++e) {
                int d = h * 64 + (q << 2) + e;
                __builtin_nontemporal_store(v[e], &ob[(size_t)d * SPB]);
            }
        }
    }

    // ---- encoding one-hot: fused zero+one-hot, lane-contiguous f32x4 nt stores
    {
        float* ebase = out + (size_t)E_OFF + (size_t)bid * (128 * NK);
        #pragma unroll
        for (int j = 0; j < 64; ++j) {
            int v   = j * 256 + tid;       // f32x4 index within block's 128x512 region
            int r   = v >> 7;
            int cb4 = (v & 127) << 2;
            int idxr = idx_s[r];
            f32x4 val;
            val[0] = (idxr == cb4    ) ? 1.0f : 0.0f;
            val[1] = (idxr == cb4 + 1) ? 1.0f : 0.0f;
            val[2] = (idxr == cb4 + 2) ? 1.0f : 0.0f;
            val[3] = (idxr == cb4 + 3) ? 1.0f : 0.0f;
            __builtin_nontemporal_store(val, (f32x4*)ebase + v);
        }
    }
}

extern "C" void kernel_launch(void* const* d_in, const int* in_sizes, int n_in,
                              void* d_out, int out_size, void* d_ws, size_t ws_size,
                              hipStream_t stream) {
    const float* x  = (const float*)d_in[0];
    const float* cb = (const float*)d_in[1];
    float* out = (float*)d_out;
    char*  ws  = (char*)d_ws;
    float* ww  = (float*)ws;                          // 2048 B
    short* cbh = (short*)(ws + 2048);                 // 131072 B

    prep_kernel<<<32, 256, 0, stream>>>(cb, ww, cbh, out);
    vq_main<<<NBLK, 256, 0, stream>>>(x, cb, ww, cbh, out);
}